// Round 7
// baseline (33.634 us; speedup 1.0000x reference)
//
#include <hip/hip_runtime.h>
#include <hip/hip_bf16.h>

#define B_    4
#define T_    4096
#define D_    2048
#define NTOK  (B_ * T_)
#define NREC  3
#define BAL_W 0.01f
#define Z_W   0.001f
#define ABLK  1024            // phaseA grid (blocks)
#define ATHR  512             // phaseA threads/block (8 waves)

typedef __attribute__((ext_vector_type(4))) float float4v;

// Phase A: one wave per token (2 tokens/wave grid-stride). W staged in LDS
// (24 KB/block) so per-thread VGPR stays low -> high occupancy -> loads stay
// in flight across the epilogue dead time. d_out is FLOAT32 (49154 elems):
//   [0, NTOK)        : selected (phase B)
//   [NTOK, 2*NTOK)   : gate, sign = inactive tag (uncompacted; fixed by B)
//   [2*NTOK, 3*NTOK) : logit0
//   [3*NTOK] aux, [3*NTOK+1] z
__global__ __launch_bounds__(ATHR) void tcr7_phaseA(
    const float* __restrict__ x,              // [NTOK, D_] f32
    const float* __restrict__ w,              // [NREC, D_] f32
    const int* __restrict__ ridx_p,
    float* __restrict__ out_f,                // d_out as f32
    float4v* __restrict__ partials)           // [ABLK] in d_ws
{
    __shared__ float s_w[NREC * D_];          // 24 KB
    {
        const float4v* src = reinterpret_cast<const float4v*>(w);
        float4v*       dst = reinterpret_cast<float4v*>(s_w);
#pragma unroll
        for (int i = 0; i < (NREC * D_ / 4) / ATHR; ++i)   // 1536/512 = 3
            dst[i * ATHR + threadIdx.x] = src[i * ATHR + threadIdx.x];
    }
    __syncthreads();

    const int ridx = ridx_p[0];
    const int jc   = ridx < (NREC - 1) ? (ridx < 0 ? 0 : ridx) : (NREC - 1);
    const int lane = threadIdx.x & 63;
    const int wv   = threadIdx.x >> 6;                     // wave in block (0..7)
    const int wid  = (blockIdx.x * ATHR + threadIdx.x) >> 6;
    const int nw   = (gridDim.x * ATHR) >> 6;              // 8192 waves

    float z2 = 0.f, c0 = 0.f, c1 = 0.f, c2 = 0.f;

    for (int t = wid; t < NTOK; t += nw) {
        const float* xp = x + (size_t)t * D_;
        float4v xv[8];
#pragma unroll
        for (int j = 0; j < 8; ++j)
            xv[j] = *reinterpret_cast<const float4v*>(xp + (j * 64 + lane) * 4);

        float a0 = 0.f, a1 = 0.f, a2 = 0.f;
#pragma unroll
        for (int j = 0; j < 8; ++j) {
            const int kb = (j * 64 + lane) * 4;
            const float4v w0 = *reinterpret_cast<const float4v*>(&s_w[kb]);
            const float4v w1 = *reinterpret_cast<const float4v*>(&s_w[D_ + kb]);
            const float4v w2 = *reinterpret_cast<const float4v*>(&s_w[2 * D_ + kb]);
#pragma unroll
            for (int e = 0; e < 4; ++e) {
                a0 = fmaf(xv[j][e], w0[e], a0);
                a1 = fmaf(xv[j][e], w1[e], a1);
                a2 = fmaf(xv[j][e], w2[e], a2);
            }
        }
#pragma unroll
        for (int off = 32; off > 0; off >>= 1) {
            a0 += __shfl_xor(a0, off);
            a1 += __shfl_xor(a1, off);
            a2 += __shfl_xor(a2, off);
        }
        if (lane == 0) {
            const float m  = fmaxf(a0, fmaxf(a1, a2));
            const float e0 = expf(a0 - m), e1 = expf(a1 - m), e2 = expf(a2 - m);
            const float s  = e0 + e1 + e2;
            const float z  = m + logf(s);
            int   assign = 0; float best = a0;
            if (a1 > best) { best = a1; assign = 1; }
            if (a2 > best) { best = a2; assign = 2; }
            const float g = (jc == 0 ? e0 : (jc == 1 ? e1 : e2)) / s;   // > 0

            out_f[NTOK + t]     = (assign >= ridx) ? g : -g;  // sign = inactive
            out_f[2 * NTOK + t] = a0;

            z2 += z * z;
            if (assign == 0) c0 += 1.f; else if (assign == 1) c1 += 1.f; else c2 += 1.f;
        }
    }

    // Block partial reduce (8 waves) -> one float4 per block. No atomics.
    __shared__ float4v s_part[ATHR / 64];
    if (lane == 0) {
        float4v p; p[0] = z2; p[1] = c0; p[2] = c1; p[3] = c2;
        s_part[wv] = p;
    }
    __syncthreads();
    if (threadIdx.x == 0) {
        float4v p = s_part[0];
#pragma unroll
        for (int i = 1; i < ATHR / 64; ++i) {
            const float4v q = s_part[i];
#pragma unroll
            for (int e = 0; e < 4; ++e) p[e] += q[e];
        }
        partials[blockIdx.x] = p;
    }
}

// Phase B: per-batch stable compaction via shuffle-based scan (2 barriers),
// plus loss reduction (block 0 only) via shuffle reduce.
__global__ __launch_bounds__(1024) void tcr7_phaseB(
    const float4v* __restrict__ partials,     // [ABLK]
    float* __restrict__ out_f)
{
    __shared__ int      s_ws[16];
    __shared__ unsigned s_sel[T_];
    __shared__ float    s_g[T_];
    __shared__ float4v  s_red[16];
    const int b    = blockIdx.x;
    const int tid  = threadIdx.x;
    const int lane = tid & 63;
    const int wv   = tid >> 6;                // 16 waves
    const int base = b * T_;

    float g[4]; int f[4]; int loc = 0;
#pragma unroll
    for (int r = 0; r < 4; ++r) {
        g[r] = out_f[NTOK + base + tid * 4 + r];
        f[r] = (g[r] > 0.f) ? 1 : 0;          // sign set => inactive
        loc += f[r];
    }
    // wave-level inclusive scan of loc
    int isc = loc;
#pragma unroll
    for (int off = 1; off < 64; off <<= 1) {
        const int u = __shfl_up(isc, off);
        if (lane >= off) isc += u;
    }
    if (lane == 63) s_ws[wv] = isc;
    __syncthreads();
    int wbase = 0, cnt = 0;
#pragma unroll
    for (int i = 0; i < 16; ++i) {
        const int v = s_ws[i];
        cnt += v;
        if (i < wv) wbase += v;
    }
    int pos = wbase + isc - loc;              // exclusive prefix for this thread
#pragma unroll
    for (int r = 0; r < 4; ++r) {
        if (f[r] && (unsigned)pos < (unsigned)T_) {
            s_sel[pos] = (unsigned)(tid * 4 + r);
            s_g[pos]   = g[r];
            ++pos;
        }
    }
    __syncthreads();

#pragma unroll
    for (int r = 0; r < 4; ++r) {
        const int k = tid + r * 1024;         // coalesced
        float selv, gv;
        if (cnt == 0) { selv = 0.f; gv = 0.f; }
        else {
            const int kk = (k < cnt) ? k : (cnt - 1);
            selv = (float)s_sel[kk];
            gv   = s_g[kk];
        }
        out_f[base + k]        = selv;        // selected
        out_f[NTOK + base + k] = gv;          // gate_weights (compacted)
    }

    // Loss reduction (block 0 contributes; barriers reached by ALL threads).
    float4v p;
    if (b == 0) p = partials[tid];            // ABLK == 1024
    else { p[0] = 0.f; p[1] = 0.f; p[2] = 0.f; p[3] = 0.f; }
#pragma unroll
    for (int off = 32; off > 0; off >>= 1) {
#pragma unroll
        for (int e = 0; e < 4; ++e) p[e] += __shfl_xor(p[e], off);
    }
    if (lane == 0) s_red[wv] = p;
    __syncthreads();
    if (b == 0 && tid == 0) {
        float4v q = s_red[0];
#pragma unroll
        for (int i = 1; i < 16; ++i) {
            const float4v r2 = s_red[i];
#pragma unroll
            for (int e = 0; e < 4; ++e) q[e] += r2[e];
        }
        const float inv = 1.0f / (float)NTOK;
        float aux = 0.f;
#pragma unroll
        for (int n = 0; n < NREC; ++n) {
            const float d = q[1 + n] * inv - (1.0f / 3.0f);
            aux = fmaf(d, d, aux);
        }
        out_f[3 * NTOK + 0] = BAL_W * aux;
        out_f[3 * NTOK + 1] = Z_W * q[0] * inv;
    }
}

extern "C" void kernel_launch(void* const* d_in, const int* in_sizes, int n_in,
                              void* d_out, int out_size, void* d_ws, size_t ws_size,
                              hipStream_t stream) {
    const float* x  = (const float*)d_in[0];
    const float* w  = (const float*)d_in[1];
    const int* ridx = (const int*)d_in[2];
    float* out_f = (float*)d_out;
    float4v* partials = (float4v*)d_ws;   // 16 KB of ws

    tcr7_phaseA<<<dim3(ABLK), dim3(ATHR), 0, stream>>>(x, w, ridx, out_f, partials);
    tcr7_phaseB<<<dim3(B_), dim3(1024), 0, stream>>>(partials, out_f);
}

// Round 8
// 32.565 us; speedup vs baseline: 1.0328x; 1.0328x over previous
//
#include <hip/hip_runtime.h>
#include <hip/hip_bf16.h>

#define B_    4
#define T_    4096
#define D_    2048
#define NTOK  (B_ * T_)
#define NREC  3
#define BAL_W 0.01f
#define Z_W   0.001f
#define ABLK  2048            // phaseA blocks
#define ATHR  256             // phaseA threads/block (4 waves); 8192 waves total

typedef __attribute__((ext_vector_type(4))) float float4v;

// Phase A: each wave owns 2 consecutive tokens (16 KB contiguous). All 16
// x-loads issued up front (max MLP); W staged in LDS, read once per j for
// both tokens; epilogue on lanes 0 and 32 in parallel. d_out FLOAT32:
//   [0, NTOK)        : selected (phase B)
//   [NTOK, 2*NTOK)   : gate, sign = inactive tag (uncompacted; fixed by B)
//   [2*NTOK, 3*NTOK) : logit0
//   [3*NTOK] aux, [3*NTOK+1] z
__global__ __launch_bounds__(ATHR) void tcr8_phaseA(
    const float* __restrict__ x,              // [NTOK, D_] f32
    const float* __restrict__ w,              // [NREC, D_] f32
    const int* __restrict__ ridx_p,
    float* __restrict__ out_f,                // d_out as f32
    float4v* __restrict__ partials)           // [ABLK] in d_ws
{
    __shared__ float s_w[NREC * D_];          // 24 KB
    {
        const float4v* src = reinterpret_cast<const float4v*>(w);
        float4v*       dst = reinterpret_cast<float4v*>(s_w);
#pragma unroll
        for (int i = 0; i < (NREC * D_ / 4) / ATHR; ++i)   // 1536/256 = 6
            dst[i * ATHR + threadIdx.x] = src[i * ATHR + threadIdx.x];
    }
    __syncthreads();

    const int ridx = ridx_p[0];
    const int jc   = ridx < (NREC - 1) ? (ridx < 0 ? 0 : ridx) : (NREC - 1);
    const int lane = threadIdx.x & 63;
    const int wv   = threadIdx.x >> 6;                     // wave in block (0..3)
    const int wid  = (blockIdx.x * ATHR + threadIdx.x) >> 6;
    const int t0   = wid * 2;                              // tokens t0, t0+1

    // Issue ALL 16 loads up front: 16 KB contiguous per wave.
    const float* xp0 = x + (size_t)t0 * D_;
    float4v xv0[8], xv1[8];
#pragma unroll
    for (int j = 0; j < 8; ++j) {
        xv0[j] = *reinterpret_cast<const float4v*>(xp0 + (j * 64 + lane) * 4);
        xv1[j] = *reinterpret_cast<const float4v*>(xp0 + D_ + (j * 64 + lane) * 4);
    }

    float a0 = 0.f, a1 = 0.f, a2 = 0.f;       // token t0
    float b0 = 0.f, b1 = 0.f, b2 = 0.f;       // token t0+1
#pragma unroll
    for (int j = 0; j < 8; ++j) {
        const int kb = (j * 64 + lane) * 4;
        const float4v w0 = *reinterpret_cast<const float4v*>(&s_w[kb]);
        const float4v w1 = *reinterpret_cast<const float4v*>(&s_w[D_ + kb]);
        const float4v w2 = *reinterpret_cast<const float4v*>(&s_w[2 * D_ + kb]);
#pragma unroll
        for (int e = 0; e < 4; ++e) {
            a0 = fmaf(xv0[j][e], w0[e], a0);
            a1 = fmaf(xv0[j][e], w1[e], a1);
            a2 = fmaf(xv0[j][e], w2[e], a2);
            b0 = fmaf(xv1[j][e], w0[e], b0);
            b1 = fmaf(xv1[j][e], w1[e], b1);
            b2 = fmaf(xv1[j][e], w2[e], b2);
        }
    }
#pragma unroll
    for (int off = 32; off > 0; off >>= 1) {
        a0 += __shfl_xor(a0, off);
        a1 += __shfl_xor(a1, off);
        a2 += __shfl_xor(a2, off);
        b0 += __shfl_xor(b0, off);
        b1 += __shfl_xor(b1, off);
        b2 += __shfl_xor(b2, off);
    }

    __shared__ float4v s_part[(ATHR / 64) * 2];
    // Lanes 0 and 32 run the epilogue in parallel (one for each token).
    if ((lane & 31) == 0) {
        const int hi = lane >> 5;              // 0 -> t0, 1 -> t0+1
        const int t  = t0 + hi;
        const float l0 = hi ? b0 : a0;
        const float l1 = hi ? b1 : a1;
        const float l2 = hi ? b2 : a2;

        const float m  = fmaxf(l0, fmaxf(l1, l2));
        const float e0 = expf(l0 - m), e1 = expf(l1 - m), e2 = expf(l2 - m);
        const float s  = e0 + e1 + e2;
        const float z  = m + logf(s);
        int   assign = 0; float best = l0;
        if (l1 > best) { best = l1; assign = 1; }
        if (l2 > best) { best = l2; assign = 2; }
        const float g = (jc == 0 ? e0 : (jc == 1 ? e1 : e2)) / s;   // > 0

        out_f[NTOK + t]     = (assign >= ridx) ? g : -g;   // sign = inactive
        out_f[2 * NTOK + t] = l0;

        float4v p;
        p[0] = z * z;
        p[1] = (assign == 0) ? 1.f : 0.f;
        p[2] = (assign == 1) ? 1.f : 0.f;
        p[3] = (assign == 2) ? 1.f : 0.f;
        s_part[wv * 2 + hi] = p;
    }
    __syncthreads();
    if (threadIdx.x == 0) {
        float4v p = s_part[0];
#pragma unroll
        for (int i = 1; i < (ATHR / 64) * 2; ++i) {
            const float4v q = s_part[i];
#pragma unroll
            for (int e = 0; e < 4; ++e) p[e] += q[e];
        }
        partials[blockIdx.x] = p;
    }
}

// Phase B: per-batch stable compaction via shuffle-based scan (2 barriers),
// plus loss reduction (block 0) via shuffle reduce.
__global__ __launch_bounds__(1024) void tcr8_phaseB(
    const float4v* __restrict__ partials,     // [ABLK]
    float* __restrict__ out_f)
{
    __shared__ int      s_ws[16];
    __shared__ unsigned s_sel[T_];
    __shared__ float    s_g[T_];
    __shared__ float4v  s_red[16];
    const int b    = blockIdx.x;
    const int tid  = threadIdx.x;
    const int lane = tid & 63;
    const int wv   = tid >> 6;                // 16 waves
    const int base = b * T_;

    float g[4]; int f[4]; int loc = 0;
#pragma unroll
    for (int r = 0; r < 4; ++r) {
        g[r] = out_f[NTOK + base + tid * 4 + r];
        f[r] = (g[r] > 0.f) ? 1 : 0;          // sign set => inactive
        loc += f[r];
    }
    int isc = loc;
#pragma unroll
    for (int off = 1; off < 64; off <<= 1) {
        const int u = __shfl_up(isc, off);
        if (lane >= off) isc += u;
    }
    if (lane == 63) s_ws[wv] = isc;
    __syncthreads();
    int wbase = 0, cnt = 0;
#pragma unroll
    for (int i = 0; i < 16; ++i) {
        const int v = s_ws[i];
        cnt += v;
        if (i < wv) wbase += v;
    }
    int pos = wbase + isc - loc;              // exclusive prefix
#pragma unroll
    for (int r = 0; r < 4; ++r) {
        if (f[r] && (unsigned)pos < (unsigned)T_) {
            s_sel[pos] = (unsigned)(tid * 4 + r);
            s_g[pos]   = g[r];
            ++pos;
        }
    }
    __syncthreads();

#pragma unroll
    for (int r = 0; r < 4; ++r) {
        const int k = tid + r * 1024;         // coalesced
        float selv, gv;
        if (cnt == 0) { selv = 0.f; gv = 0.f; }
        else {
            const int kk = (k < cnt) ? k : (cnt - 1);
            selv = (float)s_sel[kk];
            gv   = s_g[kk];
        }
        out_f[base + k]        = selv;        // selected
        out_f[NTOK + base + k] = gv;          // gate_weights (compacted)
    }

    // Loss reduction: block 0; ABLK == 2048 -> each thread folds 2 partials.
    float4v p;
    if (b == 0) {
        const float4v pa = partials[tid];
        const float4v pb = partials[tid + 1024];
#pragma unroll
        for (int e = 0; e < 4; ++e) p[e] = pa[e] + pb[e];
    } else { p[0] = 0.f; p[1] = 0.f; p[2] = 0.f; p[3] = 0.f; }
#pragma unroll
    for (int off = 32; off > 0; off >>= 1) {
#pragma unroll
        for (int e = 0; e < 4; ++e) p[e] += __shfl_xor(p[e], off);
    }
    if (lane == 0) s_red[wv] = p;
    __syncthreads();
    if (b == 0 && tid == 0) {
        float4v q = s_red[0];
#pragma unroll
        for (int i = 1; i < 16; ++i) {
            const float4v r2 = s_red[i];
#pragma unroll
            for (int e = 0; e < 4; ++e) q[e] += r2[e];
        }
        const float inv = 1.0f / (float)NTOK;
        float aux = 0.f;
#pragma unroll
        for (int n = 0; n < NREC; ++n) {
            const float d = q[1 + n] * inv - (1.0f / 3.0f);
            aux = fmaf(d, d, aux);
        }
        out_f[3 * NTOK + 0] = BAL_W * aux;
        out_f[3 * NTOK + 1] = Z_W * q[0] * inv;
    }
}

extern "C" void kernel_launch(void* const* d_in, const int* in_sizes, int n_in,
                              void* d_out, int out_size, void* d_ws, size_t ws_size,
                              hipStream_t stream) {
    const float* x  = (const float*)d_in[0];
    const float* w  = (const float*)d_in[1];
    const int* ridx = (const int*)d_in[2];
    float* out_f = (float*)d_out;
    float4v* partials = (float4v*)d_ws;   // 32 KB of ws

    tcr8_phaseA<<<dim3(ABLK), dim3(ATHR), 0, stream>>>(x, w, ridx, out_f, partials);
    tcr8_phaseB<<<dim3(B_), dim3(1024), 0, stream>>>(partials, out_f);
}

// Round 9
// 31.540 us; speedup vs baseline: 1.0664x; 1.0325x over previous
//
#include <hip/hip_runtime.h>
#include <hip/hip_bf16.h>

#define B_    4
#define T_    4096
#define D_    2048
#define NTOK  (B_ * T_)
#define NREC  3
#define BAL_W 0.01f
#define Z_W   0.001f
#define ABLK  2048            // phaseA blocks
#define ATHR  256             // phaseA threads/block (4 waves); 8192 waves total

typedef __attribute__((ext_vector_type(4))) float float4v;

// Phase A: each wave owns 2 consecutive tokens; all 16 x-loads issued up
// front as NONTEMPORAL (streaming, no-allocate) loads; W staged in LDS and
// read once per j for both tokens; epilogue on lanes 0 and 32 in parallel.
// d_out FLOAT32 (49154 elems):
//   [0, NTOK)        : selected (phase B)
//   [NTOK, 2*NTOK)   : gate, sign = inactive tag (uncompacted; fixed by B)
//   [2*NTOK, 3*NTOK) : logit0
//   [3*NTOK] aux, [3*NTOK+1] z
__global__ __launch_bounds__(ATHR) void tcr9_phaseA(
    const float* __restrict__ x,              // [NTOK, D_] f32
    const float* __restrict__ w,              // [NREC, D_] f32
    const int* __restrict__ ridx_p,
    float* __restrict__ out_f,                // d_out as f32
    float4v* __restrict__ partials)           // [ABLK] in d_ws
{
    __shared__ float s_w[NREC * D_];          // 24 KB
    {
        const float4v* src = reinterpret_cast<const float4v*>(w);
        float4v*       dst = reinterpret_cast<float4v*>(s_w);
#pragma unroll
        for (int i = 0; i < (NREC * D_ / 4) / ATHR; ++i)   // 1536/256 = 6
            dst[i * ATHR + threadIdx.x] =
                __builtin_nontemporal_load(src + i * ATHR + threadIdx.x);
    }
    __syncthreads();

    const int ridx = ridx_p[0];
    const int jc   = ridx < (NREC - 1) ? (ridx < 0 ? 0 : ridx) : (NREC - 1);
    const int lane = threadIdx.x & 63;
    const int wv   = threadIdx.x >> 6;                     // wave in block (0..3)
    const int wid  = (blockIdx.x * ATHR + threadIdx.x) >> 6;
    const int t0   = wid * 2;                              // tokens t0, t0+1

    // Issue ALL 16 loads up front: 16 KB contiguous per wave, streaming.
    const float* xp0 = x + (size_t)t0 * D_;
    float4v xv0[8], xv1[8];
#pragma unroll
    for (int j = 0; j < 8; ++j) {
        xv0[j] = __builtin_nontemporal_load(
            reinterpret_cast<const float4v*>(xp0 + (j * 64 + lane) * 4));
        xv1[j] = __builtin_nontemporal_load(
            reinterpret_cast<const float4v*>(xp0 + D_ + (j * 64 + lane) * 4));
    }

    float a0 = 0.f, a1 = 0.f, a2 = 0.f;       // token t0
    float b0 = 0.f, b1 = 0.f, b2 = 0.f;       // token t0+1
#pragma unroll
    for (int j = 0; j < 8; ++j) {
        const int kb = (j * 64 + lane) * 4;
        const float4v w0 = *reinterpret_cast<const float4v*>(&s_w[kb]);
        const float4v w1 = *reinterpret_cast<const float4v*>(&s_w[D_ + kb]);
        const float4v w2 = *reinterpret_cast<const float4v*>(&s_w[2 * D_ + kb]);
#pragma unroll
        for (int e = 0; e < 4; ++e) {
            a0 = fmaf(xv0[j][e], w0[e], a0);
            a1 = fmaf(xv0[j][e], w1[e], a1);
            a2 = fmaf(xv0[j][e], w2[e], a2);
            b0 = fmaf(xv1[j][e], w0[e], b0);
            b1 = fmaf(xv1[j][e], w1[e], b1);
            b2 = fmaf(xv1[j][e], w2[e], b2);
        }
    }
#pragma unroll
    for (int off = 32; off > 0; off >>= 1) {
        a0 += __shfl_xor(a0, off);
        a1 += __shfl_xor(a1, off);
        a2 += __shfl_xor(a2, off);
        b0 += __shfl_xor(b0, off);
        b1 += __shfl_xor(b1, off);
        b2 += __shfl_xor(b2, off);
    }

    __shared__ float4v s_part[(ATHR / 64) * 2];
    // Lanes 0 and 32 run the epilogue in parallel (one per token).
    if ((lane & 31) == 0) {
        const int hi = lane >> 5;              // 0 -> t0, 1 -> t0+1
        const int t  = t0 + hi;
        const float l0 = hi ? b0 : a0;
        const float l1 = hi ? b1 : a1;
        const float l2 = hi ? b2 : a2;

        const float m  = fmaxf(l0, fmaxf(l1, l2));
        const float e0 = expf(l0 - m), e1 = expf(l1 - m), e2 = expf(l2 - m);
        const float s  = e0 + e1 + e2;
        const float z  = m + logf(s);
        int   assign = 0; float best = l0;
        if (l1 > best) { best = l1; assign = 1; }
        if (l2 > best) { best = l2; assign = 2; }
        const float g = (jc == 0 ? e0 : (jc == 1 ? e1 : e2)) / s;   // > 0

        out_f[NTOK + t]     = (assign >= ridx) ? g : -g;   // sign = inactive
        out_f[2 * NTOK + t] = l0;

        float4v p;
        p[0] = z * z;
        p[1] = (assign == 0) ? 1.f : 0.f;
        p[2] = (assign == 1) ? 1.f : 0.f;
        p[3] = (assign == 2) ? 1.f : 0.f;
        s_part[wv * 2 + hi] = p;
    }
    __syncthreads();
    if (threadIdx.x == 0) {
        float4v p = s_part[0];
#pragma unroll
        for (int i = 1; i < (ATHR / 64) * 2; ++i) {
            const float4v q = s_part[i];
#pragma unroll
            for (int e = 0; e < 4; ++e) p[e] += q[e];
        }
        partials[blockIdx.x] = p;
    }
}

// Phase B: per-batch stable compaction via shuffle-based scan (2 barriers),
// plus loss reduction (block 0) via shuffle reduce.
__global__ __launch_bounds__(1024) void tcr9_phaseB(
    const float4v* __restrict__ partials,     // [ABLK]
    float* __restrict__ out_f)
{
    __shared__ int      s_ws[16];
    __shared__ unsigned s_sel[T_];
    __shared__ float    s_g[T_];
    __shared__ float4v  s_red[16];
    const int b    = blockIdx.x;
    const int tid  = threadIdx.x;
    const int lane = tid & 63;
    const int wv   = tid >> 6;                // 16 waves
    const int base = b * T_;

    float g[4]; int f[4]; int loc = 0;
#pragma unroll
    for (int r = 0; r < 4; ++r) {
        g[r] = out_f[NTOK + base + tid * 4 + r];
        f[r] = (g[r] > 0.f) ? 1 : 0;          // sign set => inactive
        loc += f[r];
    }
    int isc = loc;
#pragma unroll
    for (int off = 1; off < 64; off <<= 1) {
        const int u = __shfl_up(isc, off);
        if (lane >= off) isc += u;
    }
    if (lane == 63) s_ws[wv] = isc;
    __syncthreads();
    int wbase = 0, cnt = 0;
#pragma unroll
    for (int i = 0; i < 16; ++i) {
        const int v = s_ws[i];
        cnt += v;
        if (i < wv) wbase += v;
    }
    int pos = wbase + isc - loc;              // exclusive prefix
#pragma unroll
    for (int r = 0; r < 4; ++r) {
        if (f[r] && (unsigned)pos < (unsigned)T_) {
            s_sel[pos] = (unsigned)(tid * 4 + r);
            s_g[pos]   = g[r];
            ++pos;
        }
    }
    __syncthreads();

#pragma unroll
    for (int r = 0; r < 4; ++r) {
        const int k = tid + r * 1024;         // coalesced
        float selv, gv;
        if (cnt == 0) { selv = 0.f; gv = 0.f; }
        else {
            const int kk = (k < cnt) ? k : (cnt - 1);
            selv = (float)s_sel[kk];
            gv   = s_g[kk];
        }
        out_f[base + k]        = selv;        // selected
        out_f[NTOK + base + k] = gv;          // gate_weights (compacted)
    }

    // Loss reduction: block 0; ABLK == 2048 -> each thread folds 2 partials.
    float4v p;
    if (b == 0) {
        const float4v pa = partials[tid];
        const float4v pb = partials[tid + 1024];
#pragma unroll
        for (int e = 0; e < 4; ++e) p[e] = pa[e] + pb[e];
    } else { p[0] = 0.f; p[1] = 0.f; p[2] = 0.f; p[3] = 0.f; }
#pragma unroll
    for (int off = 32; off > 0; off >>= 1) {
#pragma unroll
        for (int e = 0; e < 4; ++e) p[e] += __shfl_xor(p[e], off);
    }
    if (lane == 0) s_red[wv] = p;
    __syncthreads();
    if (b == 0 && tid == 0) {
        float4v q = s_red[0];
#pragma unroll
        for (int i = 1; i < 16; ++i) {
            const float4v r2 = s_red[i];
#pragma unroll
            for (int e = 0; e < 4; ++e) q[e] += r2[e];
        }
        const float inv = 1.0f / (float)NTOK;
        float aux = 0.f;
#pragma unroll
        for (int n = 0; n < NREC; ++n) {
            const float d = q[1 + n] * inv - (1.0f / 3.0f);
            aux = fmaf(d, d, aux);
        }
        out_f[3 * NTOK + 0] = BAL_W * aux;
        out_f[3 * NTOK + 1] = Z_W * q[0] * inv;
    }
}

extern "C" void kernel_launch(void* const* d_in, const int* in_sizes, int n_in,
                              void* d_out, int out_size, void* d_ws, size_t ws_size,
                              hipStream_t stream) {
    const float* x  = (const float*)d_in[0];
    const float* w  = (const float*)d_in[1];
    const int* ridx = (const int*)d_in[2];
    float* out_f = (float*)d_out;
    float4v* partials = (float4v*)d_ws;   // 32 KB of ws

    tcr9_phaseA<<<dim3(ABLK), dim3(ATHR), 0, stream>>>(x, w, ridx, out_f, partials);
    tcr9_phaseB<<<dim3(B_), dim3(1024), 0, stream>>>(partials, out_f);
}